// Round 9
// baseline (464.553 us; speedup 1.0000x reference)
//
#include <hip/hip_runtime.h>
#include <math.h>

// Transformer-XL relative attention, fp16-MFMA, fused-softmax version.
// B=4 N=16 L=1024 D=64. Outputs: out [B,N,L,D] fp32, then weight [B,N,L,L] fp32.
// rel_shift(pos)[i,j] == pos[i, j - i + (L-1)], only j<=i survives the causal mask.
//
// R9: fuse Phases A and B into ONE phase (barriers 4 -> 3) and eliminate the
//     Phase-B LDS read-modify-write (serial ds_read_u16->add->ds_write_b16
//     chains). Gather-side rel_shift: the j-tile at c0 needs T[row][j-i+1023]
//     from p-tiles p1=c0-i0+1008 and p2=p1+16 (p2 only when c0<i0), at
//     within-tile column (ln+15-row)&15 -> recovered with one __shfl per
//     (acc,rg) since the index is uniform per 16-lane group. Each wave now
//     computes S+T for its own tile in registers and does a single masked
//     store. One global-load latency wall per block instead of two.
//     Falsified so far: occupancy(R2), store-drain(R3), VALU+L2(R5), store
//     volume(R6), spills(R7: VGPR=36), explicit ILP rotation(R8: -3.5us).

#define Bq 4
#define Nh 16
#define Lq 1024
#define Dh 64
#define TQ 16     // query rows per block
#define NT 512    // 8 waves
#define LROW 1032 // f16 row stride (2064 B = 516 dw; 516%32=4 -> 2-way banks, free;
                  // 16B-aligned for ds_read_b128)

// LDS-only barrier: wait for this wave's DS ops, then block barrier. Leaves
// global (vmcnt) traffic in flight across the barrier.
#define BAR() asm volatile("s_waitcnt lgkmcnt(0)\n\ts_barrier" ::: "memory")

typedef _Float16 h16;
typedef __attribute__((ext_vector_type(8))) _Float16 f16x8;
typedef __attribute__((ext_vector_type(4))) _Float16 f16x4;
typedef __attribute__((ext_vector_type(4))) float f32x4;

__device__ __forceinline__ f16x8 pack8h(float4 a, float4 b) {
    f16x8 o;
    o[0] = (h16)a.x; o[1] = (h16)a.y; o[2] = (h16)a.z; o[3] = (h16)a.w;
    o[4] = (h16)b.x; o[5] = (h16)b.y; o[6] = (h16)b.z; o[7] = (h16)b.w;
    return o;
}

__device__ __forceinline__ float wave_max(float v) {
    #pragma unroll
    for (int o = 32; o > 0; o >>= 1) v = fmaxf(v, __shfl_xor(v, o));
    return v;
}
__device__ __forceinline__ float wave_sum(float v) {
    #pragma unroll
    for (int o = 32; o > 0; o >>= 1) v += __shfl_xor(v, o);
    return v;
}

// ---------- prep (single dispatch): cvt K,P -> f16; transpose V -> Vt f16 ----------
// blocks 0..4095: K cvt; 4096..5119: P cvt; 5120..6143: V transpose.
__global__ __launch_bounds__(256) void prep_kernel(
    const float* __restrict__ K, const float* __restrict__ P,
    const float* __restrict__ V,
    h16* __restrict__ Kb, h16* __restrict__ Pb, h16* __restrict__ Vt)
{
    __shared__ float t[64][65];
    int b = blockIdx.x;
    int tid = threadIdx.x;
    if (b < 5120) {
        const float* src; h16* dst; int idx;
        if (b < 4096) { idx = b * 256 + tid; src = K; dst = Kb; }
        else          { idx = (b - 4096) * 256 + tid; src = P; dst = Pb; }
        float4 v = ((const float4*)src)[idx];
        f16x4 o;
        o[0] = (h16)v.x; o[1] = (h16)v.y; o[2] = (h16)v.z; o[3] = (h16)v.w;
        ((f16x4*)dst)[idx] = o;
        return;
    }
    int bv = b - 5120;
    int bn = bv >> 4, jt = bv & 15;
    int d = tid & 63, q = tid >> 6;
    const float* vb = V + ((size_t)(bn * Lq + jt * 64)) * Dh;
    #pragma unroll
    for (int r = 0; r < 16; r++) {
        int jl = r * 4 + q;
        t[jl][d] = vb[(size_t)jl * Dh + d];
    }
    __syncthreads();
    int dd = tid >> 2, jb = (tid & 3) << 4;
    f16x8 s0, s1;
    #pragma unroll
    for (int jj = 0; jj < 8; jj++) {
        s0[jj] = (h16)t[jb + jj][dd];
        s1[jj] = (h16)t[jb + 8 + jj][dd];
    }
    h16* drow = Vt + (((size_t)(bn * 64 + dd)) << 10) + (jt << 6) + jb;
    *(f16x8*)drow = s0;
    *(f16x8*)(drow + 8) = s1;
}

// ---------- main ----------
__global__ __launch_bounds__(NT, 6) void relattn_kernel(
    const float* __restrict__ QC, const float* __restrict__ QP,
    const h16* __restrict__ Kb, const h16* __restrict__ Pb,
    const h16* __restrict__ Vtb,
    float* __restrict__ out, float* __restrict__ wout)
{
    __shared__ __align__(16) h16 s_s[TQ][LROW];     // 33024 B, f16 scores then f16 W
    __shared__ __align__(16) float dscr[4][64][4];  // 4096 B, Phase D split-k combine

    const int tid  = threadIdx.x;
    const int w    = tid >> 6, lane = tid & 63;
    const int ln   = lane & 15, quad = lane >> 4;

    // XCD-contiguous remap: 4096 blocks, 8 XCDs -> 512 consecutive work items per
    // XCD (all 64 query-tiles of bn 0..7 on XCD0, etc -> Kb/Vtb/Pb stay L2-hot).
    // Within XCD: heaviest tiles (qt large = long causal rows) first -> short tail.
    const int bidx = blockIdx.x;
    const int wg   = ((bidx & 7) << 9) | (bidx >> 3);
    const int bn   = wg >> 6, qt = 63 - (wg & 63);
    const int nh   = bn & 15;
    const int i0   = qt << 4;

    // A fragments from fp32 directly: A[m=ln][k=quad*8+j]
    const float* qcrow = QC + (((size_t)(bn << 10) + i0 + ln) << 6) + (quad << 3);
    const float* qprow = QP + (((size_t)(bn << 10) + i0 + ln) << 6) + (quad << 3);
    f16x8 aC0 = pack8h(*(const float4*)qcrow,        *(const float4*)(qcrow + 4));
    f16x8 aC1 = pack8h(*(const float4*)(qcrow + 32), *(const float4*)(qcrow + 36));
    f16x8 aP0 = pack8h(*(const float4*)qprow,        *(const float4*)(qprow + 4));
    f16x8 aP1 = pack8h(*(const float4*)(qprow + 32), *(const float4*)(qprow + 36));

    // -inf fill of the never-written region j in [i0+16, 1024): 4 rows per
    // 128-thread group, f16x8 stores. Makes Phase C maskless (exp(-inf)=0).
    {
        f16x8 nf;
        #pragma unroll
        for (int k = 0; k < 8; k++) nf[k] = (h16)-INFINITY;
        int rr0 = tid >> 7;             // 0..3
        int tt  = tid & 127;            // 0..127
        int col = i0 + 16 + (tt << 3);
        if (col < 1024) {
            #pragma unroll
            for (int r = rr0; r < 16; r += 4)
                *(f16x8*)&s_s[r][col] = nf;
        }
    }

    // ---- Fused Phase AB: S = QC.K^T + rel_shift(QP.P^T), causal tiles only ----
    // Wave's j-tile c0 needs T from p-tiles p1=c0-i0+1008 and p2=p1+16 (p2 only
    // when c0<i0). Consumer (row, j=c0+ln) reads T at within-tile col
    // dl=(ln+15-row)&15: tile1 when ln<=row, tile2 when ln>row. The MFMA output
    // holds col in lane (same quad), so one __shfl per (acc,rg) recovers it.
    const h16* kbase = Kb + (((size_t)(bn << 10)) << 6) + (quad << 3);
    const h16* pbase = Pb + (((size_t)(nh << 10)) << 6) + (quad << 3);
    #pragma unroll
    for (int ct = 0; ct < 8; ct++) {
        int c0 = ((ct << 3) + w) << 4;           // interleave tiles across 8 waves
        if (c0 <= i0) {                          // live (c0 mult of 16 -> <= i1 too)
            const h16* kr = kbase + ((size_t)(c0 + ln) << 6);
            f16x8 k0 = *(const f16x8*)kr, k1 = *(const f16x8*)(kr + 32);
            int p1 = c0 - i0 + 1008;             // in [0, 1008]
            const h16* pr1 = pbase + ((size_t)(p1 + ln) << 6);
            f16x8 b10 = *(const f16x8*)pr1, b11 = *(const f16x8*)(pr1 + 32);

            f32x4 accK = {0.f, 0.f, 0.f, 0.f};
            accK = __builtin_amdgcn_mfma_f32_16x16x32_f16(aC0, k0, accK, 0, 0, 0);
            accK = __builtin_amdgcn_mfma_f32_16x16x32_f16(aC1, k1, accK, 0, 0, 0);

            f32x4 accT1 = {0.f, 0.f, 0.f, 0.f};
            accT1 = __builtin_amdgcn_mfma_f32_16x16x32_f16(aP0, b10, accT1, 0, 0, 0);
            accT1 = __builtin_amdgcn_mfma_f32_16x16x32_f16(aP1, b11, accT1, 0, 0, 0);

            f32x4 accT2 = {0.f, 0.f, 0.f, 0.f};
            if (c0 < i0) {                       // p2 = p1+16 <= 1008: in range
                const h16* pr2 = pr1 + (16ull << 6);
                f16x8 b20 = *(const f16x8*)pr2, b21 = *(const f16x8*)(pr2 + 32);
                accT2 = __builtin_amdgcn_mfma_f32_16x16x32_f16(aP0, b20, accT2, 0, 0, 0);
                accT2 = __builtin_amdgcn_mfma_f32_16x16x32_f16(aP1, b21, accT2, 0, 0, 0);
            }

            #pragma unroll
            for (int rg = 0; rg < 4; rg++) {     // C: col=ln, row=quad*4+rg
                int row = (quad << 2) + rg;
                int dl  = (ln + 15 - row) & 15;
                int src = (lane & 48) | dl;      // same quad, rotated column
                float t1 = __shfl(accT1[rg], src);
                float t2 = __shfl(accT2[rg], src);
                float tv = (ln <= row) ? t1 : t2;
                float val = accK[rg] + tv;
                // diagonal tile masks j>i; interior tiles never mask
                s_s[row][c0 + ln] = (h16)((c0 + ln <= i0 + row) ? val : -INFINITY);
            }
        }
    }
    BAR();

    // Phase D V prefetch: independent of softmax; issued here so Phase C hides
    // the global latency. lgkm-only BAR leaves them in flight.
    const int n0 = (w & 3) << 4;
    const int h  = w >> 2;
    const h16* vtb = Vtb + (((size_t)(bn << 6) + n0 + ln) << 10);
    f16x8 vb0 = *(const f16x8*)(vtb + ((h    ) << 5) + (quad << 3));
    f16x8 vb1 = *(const f16x8*)(vtb + ((h + 2) << 5) + (quad << 3));

    // ---- Phase C: maskless in-register softmax; nt-store W fp32; pack f16 ----
    // Wave w owns rows 2w, 2w+1. Lane owns j = c*256 + lane*4 + e, c=0..3, e=0..3.
    #pragma unroll
    for (int rr = 0; rr < 2; rr++) {
        int r = (w << 1) + rr;
        int i = i0 + r;
        float v[16];
        #pragma unroll
        for (int c = 0; c < 4; c++) {
            f16x4 t = *(f16x4*)&s_s[r][(c << 8) + (lane << 2)];
            v[c * 4 + 0] = (float)t[0]; v[c * 4 + 1] = (float)t[1];
            v[c * 4 + 2] = (float)t[2]; v[c * 4 + 3] = (float)t[3];
        }
        float mx = v[0];
        #pragma unroll
        for (int k = 1; k < 16; k++) mx = fmaxf(mx, v[k]);
        mx = wave_max(mx);                       // real: row always has j=0 live
        float sum = 0.f;
        #pragma unroll
        for (int k = 0; k < 16; k++) {
            float t = __expf((v[k] - mx) * 0.125f);   // exp(-inf)=0: exact mask zeros
            sum += t;
            v[k] = t;
        }
        sum = wave_sum(sum);
        float inv = __builtin_amdgcn_rcpf(sum);
        float* wrow = wout + (((size_t)(bn << 10) + i) << 10);
        #pragma unroll
        for (int c = 0; c < 4; c++) {
            int j = (c << 8) + (lane << 2);
            f32x4 e;
            e[0] = v[c * 4 + 0] * inv; e[1] = v[c * 4 + 1] * inv;
            e[2] = v[c * 4 + 2] * inv; e[3] = v[c * 4 + 3] * inv;
            __builtin_nontemporal_store(e, (f32x4*)&wrow[j]);  // W: write-once, skip L2
            f16x4 hh;
            hh[0] = (h16)e[0]; hh[1] = (h16)e[1]; hh[2] = (h16)e[2]; hh[3] = (h16)e[3];
            *(f16x4*)&s_s[r][j] = hh;            // f16 A-operand for Phase D, in-place
        }
    }
    BAR();

    // ---- Phase D: out = W . V via MFMA, split-k across wave pairs ----
    // Wave (w&3) owns output cols n0..n0+15; half h = w>>2 takes every other k-step.
    // af (LDS) and vb (global) both rotated depth-2.
    f32x4 o = {0.f, 0.f, 0.f, 0.f};
    const h16* abase = &s_s[ln][0];
    const int ksteps = (i0 + 16 + 31) >> 5;       // j <= i1 only; rest of W is 0
    f16x8 af = *(const f16x8*)(abase + (h << 5) + (quad << 3));
    for (int ks = h; ks < ksteps; ks += 2) {
        f16x8 afn = {}, vnn = {};
        if (ks + 2 < ksteps)
            afn = *(const f16x8*)(abase + ((ks + 2) << 5) + (quad << 3));
        if (ks + 4 < ksteps)
            vnn = *(const f16x8*)(vtb + ((ks + 4) << 5) + (quad << 3));
        o = __builtin_amdgcn_mfma_f32_16x16x32_f16(af, vb0, o, 0, 0, 0);
        af = afn; vb0 = vb1; vb1 = vnn;
    }
    if (h == 1)
        *(f32x4*)&dscr[w & 3][lane][0] = o;
    BAR();
    if (h == 0) {
        f32x4 o2 = *(f32x4*)&dscr[w][lane][0];
        o[0] += o2[0]; o[1] += o2[1]; o[2] += o2[2]; o[3] += o2[3];
        float* obase = out + (((size_t)(bn << 10) + i0) << 6);
        #pragma unroll
        for (int rg = 0; rg < 4; rg++)
            __builtin_nontemporal_store(
                o[rg], &obase[((size_t)((quad << 2) + rg) << 6) + n0 + ln]);
    }
}

extern "C" void kernel_launch(void* const* d_in, const int* in_sizes, int n_in,
                              void* d_out, int out_size, void* d_ws, size_t ws_size,
                              hipStream_t stream) {
    const float* qc = (const float*)d_in[0];
    const float* qp = (const float*)d_in[1];
    const float* K  = (const float*)d_in[2];
    const float* V  = (const float*)d_in[3];
    const float* P  = (const float*)d_in[4];
    // d_in[5]: causal mask, hardcoded.

    float* out  = (float*)d_out;
    float* wout = out + (size_t)Bq * Nh * Lq * Dh;

    const size_t NQ = (size_t)Bq * Nh * Lq * Dh;   // 4,194,304
    const size_t NP = (size_t)Nh * Lq * Dh;        // 1,048,576
    h16* Kb  = (h16*)d_ws;
    h16* Pb  = Kb + NQ;
    h16* Vtb = Pb + NP;                            // total 18 MB of ws

    prep_kernel<<<4096 + 1024 + 1024, 256, 0, stream>>>(K, P, V, Kb, Pb, Vtb);
    relattn_kernel<<<Bq * Nh * (Lq / TQ), NT, 0, stream>>>(qc, qp, Kb, Pb, Vtb, out, wout);
}